// Round 18
// baseline (706.848 us; speedup 1.0000x reference)
//
#include <hip/hip_runtime.h>
#include <hip/hip_bf16.h>

#define NN 50000
#define TB 512
#define NBLK 256
#define WPB 8
#define STR (NBLK * WPB)  // 2048 waves; pair stride 2*STR
static constexpr float EPS = 1e-5f;

typedef _Float16 h2 __attribute__((ext_vector_type(2)));
typedef _Float16 half8 __attribute__((ext_vector_type(8)));
typedef __attribute__((ext_vector_type(16))) float f32x16;
typedef unsigned int u32;

// LDS frag table (1 frag = 64 lanes * 16B = 1 KB). No bias K-slots.
#define OFF_G2 0
#define OFF_G3 16
#define OFF_F1 32
#define OFF_F2 48
#define OFF_W3 64
#define NFRAGS 80  // 80 KB

__device__ __forceinline__ h2 pkh(float a, float b) {
  return __builtin_bit_cast(h2, __builtin_amdgcn_cvt_pkrtz(a, b));
}
__device__ __forceinline__ u32 hbits(h2 x) { return __builtin_bit_cast(u32, x); }
__device__ __forceinline__ h2 h2of(u32 x) { return __builtin_bit_cast(h2, x); }
__device__ __forceinline__ f32x16 zero16() {
  f32x16 z;
#pragma unroll
  for (int i = 0; i < 16; ++i) z[i] = 0.f;
  return z;
}
#define MFMA __builtin_amdgcn_mfma_f32_32x32x16_f16

// Stage A-frags (W^T) to LDS as f16. Lane l: A[row=l&31][k=8*(l>>5)+j].
template <int IN, int OUT>
__device__ __forceinline__ void stage(const float* __restrict__ W,
                                      uint4* __restrict__ lds, int fragoff,
                                      float scale, int tid) {
  constexpr int KS = IN / 16, MT = OUT / 32;
  constexpr int ENT = MT * KS * 64;
  for (int e = tid; e < ENT; e += TB) {
    int lane = e & 63, f = e >> 6;
    int mt = f / KS, ks = f - mt * KS;
    int h = lane >> 5, och = mt * 32 + (lane & 31);
    int k0 = ks * 16 + h * 8;
    u32 d[4];
#pragma unroll
    for (int p = 0; p < 4; ++p)
      d[p] = hbits(pkh(W[(k0 + 2 * p) * OUT + och] * scale,
                       W[(k0 + 2 * p + 1) * OUT + och] * scale));
    lds[(fragoff + f) * 64 + lane] = make_uint4(d[0], d[1], d[2], d[3]);
  }
}

__device__ __forceinline__ half8 rdfrag(const uint4* __restrict__ lds,
                                        int fragidx, int lane) {
  return __builtin_bit_cast(half8, lds[fragidx * 64 + lane]);
}

__device__ __forceinline__ half8 mkfrag(u32 a, u32 b, u32 c, u32 d) {
  return __builtin_bit_cast(half8, make_uint4(a, b, c, d));
}

// LN(64)+lrelu, output packed straight into B-frags (merged affine+to_bfr).
// Stats in f32 (bias added & stored back); affine/lrelu in packed f16.
__device__ __forceinline__ void ln_pack64_dual(
    f32x16* A, f32x16* B, const float* __restrict__ bias,
    const float* __restrict__ gam, const float* __restrict__ bet, int lane,
    half8* kinA, half8* kinB) {
  const int h = (lane >> 5) & 1;
  float sA = 0.f, qA = 0.f, sB = 0.f, qB = 0.f;
#pragma unroll
  for (int mt = 0; mt < 2; ++mt)
#pragma unroll
    for (int rq = 0; rq < 4; ++rq) {
      const float4 b4 = *(const float4*)(bias + 32 * mt + 8 * rq + 4 * h);
      const float bb[4] = {b4.x, b4.y, b4.z, b4.w};
#pragma unroll
      for (int c = 0; c < 4; ++c) {
        float va = A[mt][4 * rq + c] + bb[c];
        float vb = B[mt][4 * rq + c] + bb[c];
        A[mt][4 * rq + c] = va;
        B[mt][4 * rq + c] = vb;
        sA += va; qA += va * va;
        sB += vb; qB += vb * vb;
      }
    }
  sA += __shfl_xor(sA, 32); qA += __shfl_xor(qA, 32);
  sB += __shfl_xor(sB, 32); qB += __shfl_xor(qB, 32);
  const float mA = sA * (1.f / 64.f);
  const float iA = rsqrtf(qA * (1.f / 64.f) - mA * mA + EPS);
  const float mB = sB * (1.f / 64.f);
  const float iB = rsqrtf(qB * (1.f / 64.f) - mB * mB + EPS);
  const h2 iA2 = pkh(iA, iA), nA2 = pkh(-mA * iA, -mA * iA);
  const h2 iB2 = pkh(iB, iB), nB2 = pkh(-mB * iB, -mB * iB);
  const h2 c02 = pkh(0.2f, 0.2f);
#pragma unroll
  for (int mt = 0; mt < 2; ++mt)
#pragma unroll
    for (int t2 = 0; t2 < 2; ++t2) {
      const int q0 = t2 * 8;
      const float4 g0 = *(const float4*)(gam + 32 * mt + 2 * q0 + 4 * h);
      const float4 g1 = *(const float4*)(gam + 32 * mt + 2 * q0 + 8 + 4 * h);
      const float4 e0 = *(const float4*)(bet + 32 * mt + 2 * q0 + 4 * h);
      const float4 e1 = *(const float4*)(bet + 32 * mt + 2 * q0 + 8 + 4 * h);
      const float GG[8] = {g0.x, g0.y, g0.z, g0.w, g1.x, g1.y, g1.z, g1.w};
      const float CC[8] = {e0.x, e0.y, e0.z, e0.w, e1.x, e1.y, e1.z, e1.w};
      u32 PA[4], PB[4];
#pragma unroll
      for (int p = 0; p < 4; ++p) {
        const h2 g2 = pkh(GG[2 * p], GG[2 * p + 1]);
        const h2 e2 = pkh(CC[2 * p], CC[2 * p + 1]);
        h2 xa = pkh(A[mt][q0 + 2 * p], A[mt][q0 + 2 * p + 1]);
        h2 xb = pkh(B[mt][q0 + 2 * p], B[mt][q0 + 2 * p + 1]);
        h2 ya = (xa * iA2 + nA2) * g2 + e2;
        h2 yb = (xb * iB2 + nB2) * g2 + e2;
        ya = __builtin_elementwise_max(ya, ya * c02);
        yb = __builtin_elementwise_max(yb, yb * c02);
        PA[p] = hbits(ya);
        PB[p] = hbits(yb);
      }
      auto sa1 = __builtin_amdgcn_permlane32_swap((int)PA[0], (int)PA[2], false, false);
      auto sa2 = __builtin_amdgcn_permlane32_swap((int)PA[1], (int)PA[3], false, false);
      auto sb1 = __builtin_amdgcn_permlane32_swap((int)PB[0], (int)PB[2], false, false);
      auto sb2 = __builtin_amdgcn_permlane32_swap((int)PB[1], (int)PB[3], false, false);
      kinA[2 * mt + t2] = mkfrag((u32)sa1[0], (u32)sa2[0], (u32)sa1[1], (u32)sa2[1]);
      kinB[2 * mt + t2] = mkfrag((u32)sb1[0], (u32)sb2[0], (u32)sb1[1], (u32)sb2[1]);
    }
}

// bias + pack straight into B-frags (g3 output: no LN/act).
__device__ __forceinline__ void bias_pack64_dual(const f32x16* A, const f32x16* B,
                                                 const float* __restrict__ bias,
                                                 int lane, half8* kinA,
                                                 half8* kinB) {
  const int h = (lane >> 5) & 1;
#pragma unroll
  for (int mt = 0; mt < 2; ++mt)
#pragma unroll
    for (int t2 = 0; t2 < 2; ++t2) {
      const int q0 = t2 * 8;
      const float4 b0 = *(const float4*)(bias + 32 * mt + 2 * q0 + 4 * h);
      const float4 b1 = *(const float4*)(bias + 32 * mt + 2 * q0 + 8 + 4 * h);
      const float BBv[8] = {b0.x, b0.y, b0.z, b0.w, b1.x, b1.y, b1.z, b1.w};
      u32 PA[4], PB[4];
#pragma unroll
      for (int p = 0; p < 4; ++p) {
        PA[p] = hbits(pkh(A[mt][q0 + 2 * p] + BBv[2 * p],
                          A[mt][q0 + 2 * p + 1] + BBv[2 * p + 1]));
        PB[p] = hbits(pkh(B[mt][q0 + 2 * p] + BBv[2 * p],
                          B[mt][q0 + 2 * p + 1] + BBv[2 * p + 1]));
      }
      auto sa1 = __builtin_amdgcn_permlane32_swap((int)PA[0], (int)PA[2], false, false);
      auto sa2 = __builtin_amdgcn_permlane32_swap((int)PA[1], (int)PA[3], false, false);
      auto sb1 = __builtin_amdgcn_permlane32_swap((int)PB[0], (int)PB[2], false, false);
      auto sb2 = __builtin_amdgcn_permlane32_swap((int)PB[1], (int)PB[3], false, false);
      kinA[2 * mt + t2] = mkfrag((u32)sa1[0], (u32)sa2[0], (u32)sa1[1], (u32)sa2[1]);
      kinB[2 * mt + t2] = mkfrag((u32)sb1[0], (u32)sb2[0], (u32)sb1[1], (u32)sb2[1]);
    }
}

// Dual fused [64->128 + bias + LN + lrelu] streamed into [128->64].
// SINGLE-PASS: pre-LN activations cached as packed f16 (px, 32 u32/chain);
// affine/lrelu runs directly on the packed pairs. px is compile-time indexed.
__device__ __forceinline__ void fused128_dual(
    const half8* kinA, const half8* kinB, const float* __restrict__ bias,
    const float* __restrict__ gam, const float* __restrict__ bet,
    const uint4* __restrict__ lds, int inOff, int outOff, f32x16* outA,
    f32x16* outB, int lane) {
  const int h = (lane >> 5) & 1;
  float sA = 0.f, qA = 0.f, sB = 0.f, qB = 0.f;
  u32 pxA[4][8], pxB[4][8];
#pragma unroll
  for (int mt = 0; mt < 4; ++mt) {
    f32x16 a = zero16(), b = zero16();
#pragma unroll
    for (int ks = 0; ks < 4; ++ks) {
      const half8 wf = rdfrag(lds, inOff + mt * 4 + ks, lane);
      a = MFMA(wf, kinA[ks], a, 0, 0, 0);
      b = MFMA(wf, kinB[ks], b, 0, 0, 0);
    }
#pragma unroll
    for (int rq = 0; rq < 4; ++rq) {
      const float4 b4 = *(const float4*)(bias + 32 * mt + 8 * rq + 4 * h);
      float v0 = a[4 * rq + 0] + b4.x, v1 = a[4 * rq + 1] + b4.y;
      float v2 = a[4 * rq + 2] + b4.z, v3 = a[4 * rq + 3] + b4.w;
      float w0 = b[4 * rq + 0] + b4.x, w1 = b[4 * rq + 1] + b4.y;
      float w2 = b[4 * rq + 2] + b4.z, w3 = b[4 * rq + 3] + b4.w;
      sA += (v0 + v1) + (v2 + v3);
      qA += (v0 * v0 + v1 * v1) + (v2 * v2 + v3 * v3);
      sB += (w0 + w1) + (w2 + w3);
      qB += (w0 * w0 + w1 * w1) + (w2 * w2 + w3 * w3);
      pxA[mt][2 * rq + 0] = hbits(pkh(v0, v1));
      pxA[mt][2 * rq + 1] = hbits(pkh(v2, v3));
      pxB[mt][2 * rq + 0] = hbits(pkh(w0, w1));
      pxB[mt][2 * rq + 1] = hbits(pkh(w2, w3));
    }
  }
  sA += __shfl_xor(sA, 32); qA += __shfl_xor(qA, 32);
  sB += __shfl_xor(sB, 32); qB += __shfl_xor(qB, 32);
  const float mA = sA * (1.f / 128.f);
  const float iA = rsqrtf(qA * (1.f / 128.f) - mA * mA + EPS);
  const float mB = sB * (1.f / 128.f);
  const float iB = rsqrtf(qB * (1.f / 128.f) - mB * mB + EPS);
  const h2 iA2 = pkh(iA, iA), nA2 = pkh(-mA * iA, -mA * iA);
  const h2 iB2 = pkh(iB, iB), nB2 = pkh(-mB * iB, -mB * iB);
  const h2 c02 = pkh(0.2f, 0.2f);
  // ---- affine/lrelu on packed pairs, stream into OUT layer ----
  outA[0] = zero16(); outA[1] = zero16();
  outB[0] = zero16(); outB[1] = zero16();
#pragma unroll
  for (int mt = 0; mt < 4; ++mt) {
#pragma unroll
    for (int u = 0; u < 2; ++u) {
      const int c0 = 32 * mt + 16 * u + 4 * h;
      const float4 ga4 = *(const float4*)(gam + c0);
      const float4 gb4 = *(const float4*)(gam + c0 + 8);
      const float4 ca4 = *(const float4*)(bet + c0);
      const float4 cb4 = *(const float4*)(bet + c0 + 8);
      const float GG[8] = {ga4.x, ga4.y, ga4.z, ga4.w, gb4.x, gb4.y, gb4.z, gb4.w};
      const float CC[8] = {ca4.x, ca4.y, ca4.z, ca4.w, cb4.x, cb4.y, cb4.z, cb4.w};
      u32 PA[4], PB[4];
#pragma unroll
      for (int p = 0; p < 4; ++p) {
        const h2 g2 = pkh(GG[2 * p], GG[2 * p + 1]);
        const h2 e2 = pkh(CC[2 * p], CC[2 * p + 1]);
        h2 xa = h2of(pxA[mt][4 * u + p]);
        h2 xb = h2of(pxB[mt][4 * u + p]);
        h2 ya = (xa * iA2 + nA2) * g2 + e2;
        h2 yb = (xb * iB2 + nB2) * g2 + e2;
        ya = __builtin_elementwise_max(ya, ya * c02);
        yb = __builtin_elementwise_max(yb, yb * c02);
        PA[p] = hbits(ya);
        PB[p] = hbits(yb);
      }
      auto sa1 = __builtin_amdgcn_permlane32_swap((int)PA[0], (int)PA[2], false, false);
      auto sa2 = __builtin_amdgcn_permlane32_swap((int)PA[1], (int)PA[3], false, false);
      auto sb1 = __builtin_amdgcn_permlane32_swap((int)PB[0], (int)PB[2], false, false);
      auto sb2 = __builtin_amdgcn_permlane32_swap((int)PB[1], (int)PB[3], false, false);
      const half8 frA = mkfrag((u32)sa1[0], (u32)sa2[0], (u32)sa1[1], (u32)sa2[1]);
      const half8 frB = mkfrag((u32)sb1[0], (u32)sb2[0], (u32)sb1[1], (u32)sb2[1]);
      const int t = 2 * mt + u;
      const half8 w0 = rdfrag(lds, outOff + t, lane);
      const half8 w1 = rdfrag(lds, outOff + 8 + t, lane);
      outA[0] = MFMA(w0, frA, outA[0], 0, 0, 0);
      outA[1] = MFMA(w1, frA, outA[1], 0, 0, 0);
      outB[0] = MFMA(w0, frB, outB[0], 0, 0, 0);
      outB[1] = MFMA(w1, frB, outB[1], 0, 0, 0);
    }
  }
}

extern "C" __global__ void __launch_bounds__(TB)
    __attribute__((amdgpu_waves_per_eu(2, 2)))  // 2 waves/EU -> 256-VGPR budget
lfa_mfma(const float* __restrict__ pf, const float* __restrict__ geom,
         const int* __restrict__ nidx,
         const float* __restrict__ g_w1, const float* __restrict__ g_b1,
         const float* __restrict__ g_ls1, const float* __restrict__ g_lb1,
         const float* __restrict__ g_w2, const float* __restrict__ g_b2,
         const float* __restrict__ g_ls2, const float* __restrict__ g_lb2,
         const float* __restrict__ g_w3, const float* __restrict__ g_b3,
         const float* __restrict__ f_w1, const float* __restrict__ f_b1,
         const float* __restrict__ f_ls1, const float* __restrict__ f_lb1,
         const float* __restrict__ f_w2, const float* __restrict__ f_b2,
         const float* __restrict__ f_ls2, const float* __restrict__ f_lb2,
         const float* __restrict__ f_w3, const float* __restrict__ f_b3,
         float* __restrict__ out) {
  extern __shared__ uint4 lds[];
  const int tid = threadIdx.x;

  stage<64, 128>(g_w2, lds, OFF_G2, 1.f, tid);
  stage<128, 64>(g_w3, lds, OFF_G3, 1.f, tid);
  stage<128, 64>(f_w1, lds, OFF_F1, 1.f, tid);
  stage<64, 128>(f_w2, lds, OFF_F2, 1.f, tid);
  stage<128, 64>(f_w3, lds, OFF_W3, 1.f / 16.f, tid);  // fold mean over K
  __syncthreads();

  const int lane = tid & 63;
  const int w = tid >> 6;
  const int h = lane >> 5;
  const int p31 = lane & 31;

  // gL1 A-frags (4 -> 64, K padded to 16)
  half8 a1[2];
#pragma unroll
  for (int mt = 0; mt < 2; ++mt) {
    const int och = 32 * mt + p31;
    a1[mt] = mkfrag(h ? 0u : hbits(pkh(g_w1[0 * 64 + och], g_w1[1 * 64 + och])),
                    h ? 0u : hbits(pkh(g_w1[2 * 64 + och], g_w1[3 * 64 + och])),
                    0u, 0u);
  }

  half8 kinA[4], kinB[4];

  for (int t0 = blockIdx.x * WPB + w; t0 < NN; t0 += 2 * STR) {
    asm volatile("" ::: "memory");  // forbid LICM of any in-loop load
    const int tileA = t0;
    const bool hasB = (t0 + STR) < NN;            // wave-uniform
    const int tileB = hasB ? (t0 + STR) : tileA;  // redundant compute on tail
    const int rrowA = tileA * 32 + p31;
    const int rrowB = tileB * 32 + p31;
    const int bbA = tileA / 25000;
    const int bbB = tileB / 25000;

    // early-issue gather indices (addresses ready under the geom phase)
    const int idxA = nidx[rrowA];
    const int idxB = nidx[rrowB];
    const float* prA = pf + ((size_t)bbA * NN + idxA) * 64;
    const float* prB = pf + ((size_t)bbB * NN + idxB) * 64;

    // ---- geom L1: 4 -> 64 (dual) ----
    const float4 gA = *(const float4*)(geom + (size_t)rrowA * 4);
    const float4 gB = *(const float4*)(geom + (size_t)rrowB * 4);
    const half8 gfA = mkfrag(h ? 0u : hbits(pkh(gA.x, gA.y)),
                             h ? 0u : hbits(pkh(gA.z, gA.w)), 0u, 0u);
    const half8 gfB = mkfrag(h ? 0u : hbits(pkh(gB.x, gB.y)),
                             h ? 0u : hbits(pkh(gB.z, gB.w)), 0u, 0u);
    f32x16 accA[2], accB[2];
#pragma unroll
    for (int mt = 0; mt < 2; ++mt) {
      accA[mt] = MFMA(a1[mt], gfA, zero16(), 0, 0, 0);
      accB[mt] = MFMA(a1[mt], gfB, zero16(), 0, 0, 0);
    }
    ln_pack64_dual(accA, accB, g_b1, g_ls1, g_lb1, lane, kinA, kinB);

    // ---- geom L2 -> geom L3 (dual fused, single-pass) ----
    fused128_dual(kinA, kinB, g_b2, g_ls2, g_lb2, lds, OFF_G2, OFF_G3, accA,
                  accB, lane);
    bias_pack64_dual(accA, accB, g_b3, lane, kinA, kinB);

    // ---- feat L1: 128 -> 64 (dual; first half from kin, gather streamed) ----
#pragma unroll
    for (int mt = 0; mt < 2; ++mt) {
      f32x16 ta = zero16(), tb = zero16();
#pragma unroll
      for (int ks = 0; ks < 4; ++ks) {
        const half8 wf = rdfrag(lds, OFF_F1 + mt * 8 + ks, lane);
        ta = MFMA(wf, kinA[ks], ta, 0, 0, 0);
        tb = MFMA(wf, kinB[ks], tb, 0, 0, 0);
      }
      accA[mt] = ta;
      accB[mt] = tb;
    }
    {
#pragma unroll
      for (int t = 0; t < 4; ++t) {
        const float4 xA = *(const float4*)(prA + 16 * t + 8 * h);
        const float4 yA = *(const float4*)(prA + 16 * t + 8 * h + 4);
        const float4 xB = *(const float4*)(prB + 16 * t + 8 * h);
        const float4 yB = *(const float4*)(prB + 16 * t + 8 * h + 4);
        const half8 fA = mkfrag(hbits(pkh(xA.x, xA.y)), hbits(pkh(xA.z, xA.w)),
                                hbits(pkh(yA.x, yA.y)), hbits(pkh(yA.z, yA.w)));
        const half8 fB = mkfrag(hbits(pkh(xB.x, xB.y)), hbits(pkh(xB.z, xB.w)),
                                hbits(pkh(yB.x, yB.y)), hbits(pkh(yB.z, yB.w)));
        const half8 w0 = rdfrag(lds, OFF_F1 + 4 + t, lane);
        const half8 w1 = rdfrag(lds, OFF_F1 + 12 + t, lane);
        accA[0] = MFMA(w0, fA, accA[0], 0, 0, 0);
        accA[1] = MFMA(w1, fA, accA[1], 0, 0, 0);
        accB[0] = MFMA(w0, fB, accB[0], 0, 0, 0);
        accB[1] = MFMA(w1, fB, accB[1], 0, 0, 0);
      }
    }
    ln_pack64_dual(accA, accB, f_b1, f_ls1, f_lb1, lane, kinA, kinB);

    // ---- feat L2 -> final/16 (dual fused, single-pass) ----
    fused128_dual(kinA, kinB, f_b2, f_ls2, f_lb2, lds, OFF_F2, OFF_W3, accA,
                  accB, lane);

    // ---- sum over 16 k-columns (both), add f_b3 at store ----
#pragma unroll
    for (int mt = 0; mt < 2; ++mt)
#pragma unroll
      for (int r = 0; r < 16; ++r) {
        float va = accA[mt][r];
        float vb = accB[mt][r];
        va += __shfl_xor(va, 1); vb += __shfl_xor(vb, 1);
        va += __shfl_xor(va, 2); vb += __shfl_xor(vb, 2);
        va += __shfl_xor(va, 4); vb += __shfl_xor(vb, 4);
        va += __shfl_xor(va, 8); vb += __shfl_xor(vb, 8);
        accA[mt][r] = va;
        accB[mt][r] = vb;
      }
    if ((lane & 15) < 4) {
      const int c = lane & 15;
      const int bn = (lane >> 4) & 1;
      const size_t rowA = (size_t)tileA * 2 + bn;
      const size_t rowB = (size_t)tileB * 2 + bn;
#pragma unroll
      for (int mt = 0; mt < 2; ++mt) {
        const float4 bq = *(const float4*)(f_b3 + 32 * mt + 8 * c + 4 * h);
        const float4 vA =
            (c == 0) ? make_float4(accA[mt][0], accA[mt][1], accA[mt][2], accA[mt][3])
          : (c == 1) ? make_float4(accA[mt][4], accA[mt][5], accA[mt][6], accA[mt][7])
          : (c == 2) ? make_float4(accA[mt][8], accA[mt][9], accA[mt][10], accA[mt][11])
                     : make_float4(accA[mt][12], accA[mt][13], accA[mt][14], accA[mt][15]);
        *(float4*)(out + rowA * 64 + 32 * mt + 8 * c + 4 * h) =
            make_float4(vA.x + bq.x, vA.y + bq.y, vA.z + bq.z, vA.w + bq.w);
        if (hasB) {
          const float4 vB =
              (c == 0) ? make_float4(accB[mt][0], accB[mt][1], accB[mt][2], accB[mt][3])
            : (c == 1) ? make_float4(accB[mt][4], accB[mt][5], accB[mt][6], accB[mt][7])
            : (c == 2) ? make_float4(accB[mt][8], accB[mt][9], accB[mt][10], accB[mt][11])
                       : make_float4(accB[mt][12], accB[mt][13], accB[mt][14], accB[mt][15]);
          *(float4*)(out + rowB * 64 + 32 * mt + 8 * c + 4 * h) =
              make_float4(vB.x + bq.x, vB.y + bq.y, vB.z + bq.z, vB.w + bq.w);
        }
      }
    }
  }
}

extern "C" void kernel_launch(void* const* d_in, const int* in_sizes, int n_in,
                              void* d_out, int out_size, void* d_ws, size_t ws_size,
                              hipStream_t stream) {
  const float* pf = (const float*)d_in[0];
  const float* geom = (const float*)d_in[1];
  const int* nidx = (const int*)d_in[2];
  const float* g_w1 = (const float*)d_in[3];
  const float* g_b1 = (const float*)d_in[4];
  const float* g_ls1 = (const float*)d_in[5];
  const float* g_lb1 = (const float*)d_in[6];
  const float* g_w2 = (const float*)d_in[7];
  const float* g_b2 = (const float*)d_in[8];
  const float* g_ls2 = (const float*)d_in[9];
  const float* g_lb2 = (const float*)d_in[10];
  const float* g_w3 = (const float*)d_in[11];
  const float* g_b3 = (const float*)d_in[12];
  const float* f_w1 = (const float*)d_in[13];
  const float* f_b1 = (const float*)d_in[14];
  const float* f_ls1 = (const float*)d_in[15];
  const float* f_lb1 = (const float*)d_in[16];
  const float* f_w2 = (const float*)d_in[17];
  const float* f_b2 = (const float*)d_in[18];
  const float* f_ls2 = (const float*)d_in[19];
  const float* f_lb2 = (const float*)d_in[20];
  const float* f_w3 = (const float*)d_in[21];
  const float* f_b3 = (const float*)d_in[22];

  const int shmem = NFRAGS * 64 * 16;  // 81920 B
  lfa_mfma<<<NBLK, TB, shmem, stream>>>(
      pf, geom, nidx, g_w1, g_b1, g_ls1, g_lb1, g_w2, g_b2, g_ls2, g_lb2, g_w3,
      g_b3, f_w1, f_b1, f_ls1, f_lb1, f_w2, f_b2, f_ls2, f_lb2, f_w3, f_b3,
      (float*)d_out);
}

// Round 19
// 327.405 us; speedup vs baseline: 2.1589x; 2.1589x over previous
//
#include <hip/hip_runtime.h>
#include <hip/hip_bf16.h>

#define NN 50000
#define TB 512
#define NBLK 256
#define WPB 8
#define STR (NBLK * WPB)  // 2048 waves; pair stride 2*STR
static constexpr float EPS = 1e-5f;

typedef _Float16 h2 __attribute__((ext_vector_type(2)));
typedef _Float16 half8 __attribute__((ext_vector_type(8)));
typedef float f2 __attribute__((ext_vector_type(2)));
typedef __attribute__((ext_vector_type(16))) float f32x16;
typedef unsigned int u32;

// LDS frag table (1 frag = 64 lanes * 16B = 1 KB). No bias K-slots.
#define OFF_G2 0
#define OFF_G3 16
#define OFF_F1 32
#define OFF_F2 48
#define OFF_W3 64
#define NFRAGS 80  // 80 KB

__device__ __forceinline__ h2 pkh(float a, float b) {
  return __builtin_bit_cast(h2, __builtin_amdgcn_cvt_pkrtz(a, b));
}
__device__ __forceinline__ h2 pkh2(f2 v) {
  return __builtin_bit_cast(h2, __builtin_amdgcn_cvt_pkrtz(v.x, v.y));
}
__device__ __forceinline__ u32 hbits(h2 x) { return __builtin_bit_cast(u32, x); }
__device__ __forceinline__ f32x16 zero16() {
  f32x16 z;
#pragma unroll
  for (int i = 0; i < 16; ++i) z[i] = 0.f;
  return z;
}
#define MFMA __builtin_amdgcn_mfma_f32_32x32x16_f16

// Stage A-frags (W^T) to LDS as f16. Lane l: A[row=l&31][k=8*(l>>5)+j].
template <int IN, int OUT>
__device__ __forceinline__ void stage(const float* __restrict__ W,
                                      uint4* __restrict__ lds, int fragoff,
                                      float scale, int tid) {
  constexpr int KS = IN / 16, MT = OUT / 32;
  constexpr int ENT = MT * KS * 64;
  for (int e = tid; e < ENT; e += TB) {
    int lane = e & 63, f = e >> 6;
    int mt = f / KS, ks = f - mt * KS;
    int h = lane >> 5, och = mt * 32 + (lane & 31);
    int k0 = ks * 16 + h * 8;
    u32 d[4];
#pragma unroll
    for (int p = 0; p < 4; ++p)
      d[p] = hbits(pkh(W[(k0 + 2 * p) * OUT + och] * scale,
                       W[(k0 + 2 * p + 1) * OUT + och] * scale));
    lds[(fragoff + f) * 64 + lane] = make_uint4(d[0], d[1], d[2], d[3]);
  }
}

__device__ __forceinline__ half8 rdfrag(const uint4* __restrict__ lds,
                                        int fragidx, int lane) {
  return __builtin_bit_cast(half8, lds[fragidx * 64 + lane]);
}

__device__ __forceinline__ half8 mkfrag(u32 a, u32 b, u32 c, u32 d) {
  return __builtin_bit_cast(half8, make_uint4(a, b, c, d));
}

// LN(64)+lrelu, output packed straight into B-frags.
// Stats in packed f32 (v_pk_add/v_pk_fma); affine/lrelu in packed f16.
__device__ __forceinline__ void ln_pack64_dual(
    f32x16* A, f32x16* B, const float* __restrict__ bias,
    const float* __restrict__ gam, const float* __restrict__ bet, int lane,
    half8* kinA, half8* kinB) {
  const int h = (lane >> 5) & 1;
  f2 sA2 = {0.f, 0.f}, qA2 = {0.f, 0.f}, sB2 = {0.f, 0.f}, qB2 = {0.f, 0.f};
#pragma unroll
  for (int mt = 0; mt < 2; ++mt)
#pragma unroll
    for (int rq = 0; rq < 4; ++rq) {
      const float4 b4 = *(const float4*)(bias + 32 * mt + 8 * rq + 4 * h);
      const f2 b01 = {b4.x, b4.y}, b23 = {b4.z, b4.w};
      f2 va01 = f2{A[mt][4 * rq + 0], A[mt][4 * rq + 1]} + b01;
      f2 va23 = f2{A[mt][4 * rq + 2], A[mt][4 * rq + 3]} + b23;
      f2 vb01 = f2{B[mt][4 * rq + 0], B[mt][4 * rq + 1]} + b01;
      f2 vb23 = f2{B[mt][4 * rq + 2], B[mt][4 * rq + 3]} + b23;
      A[mt][4 * rq + 0] = va01.x; A[mt][4 * rq + 1] = va01.y;
      A[mt][4 * rq + 2] = va23.x; A[mt][4 * rq + 3] = va23.y;
      B[mt][4 * rq + 0] = vb01.x; B[mt][4 * rq + 1] = vb01.y;
      B[mt][4 * rq + 2] = vb23.x; B[mt][4 * rq + 3] = vb23.y;
      sA2 += va01 + va23;
      qA2 = va01 * va01 + qA2;
      qA2 = va23 * va23 + qA2;
      sB2 += vb01 + vb23;
      qB2 = vb01 * vb01 + qB2;
      qB2 = vb23 * vb23 + qB2;
    }
  float sA = sA2.x + sA2.y, qA = qA2.x + qA2.y;
  float sB = sB2.x + sB2.y, qB = qB2.x + qB2.y;
  sA += __shfl_xor(sA, 32); qA += __shfl_xor(qA, 32);
  sB += __shfl_xor(sB, 32); qB += __shfl_xor(qB, 32);
  const float mA = sA * (1.f / 64.f);
  const float iA = rsqrtf(qA * (1.f / 64.f) - mA * mA + EPS);
  const float mB = sB * (1.f / 64.f);
  const float iB = rsqrtf(qB * (1.f / 64.f) - mB * mB + EPS);
  const h2 iA2 = pkh(iA, iA), nA2 = pkh(-mA * iA, -mA * iA);
  const h2 iB2 = pkh(iB, iB), nB2 = pkh(-mB * iB, -mB * iB);
  const h2 c02 = pkh(0.2f, 0.2f);
#pragma unroll
  for (int mt = 0; mt < 2; ++mt)
#pragma unroll
    for (int t2 = 0; t2 < 2; ++t2) {
      const int q0 = t2 * 8;
      const float4 g0 = *(const float4*)(gam + 32 * mt + 2 * q0 + 4 * h);
      const float4 g1 = *(const float4*)(gam + 32 * mt + 2 * q0 + 8 + 4 * h);
      const float4 e0 = *(const float4*)(bet + 32 * mt + 2 * q0 + 4 * h);
      const float4 e1 = *(const float4*)(bet + 32 * mt + 2 * q0 + 8 + 4 * h);
      const float GG[8] = {g0.x, g0.y, g0.z, g0.w, g1.x, g1.y, g1.z, g1.w};
      const float CC[8] = {e0.x, e0.y, e0.z, e0.w, e1.x, e1.y, e1.z, e1.w};
      u32 PA[4], PB[4];
#pragma unroll
      for (int p = 0; p < 4; ++p) {
        const h2 g2 = pkh(GG[2 * p], GG[2 * p + 1]);
        const h2 e2 = pkh(CC[2 * p], CC[2 * p + 1]);
        h2 xa = pkh(A[mt][q0 + 2 * p], A[mt][q0 + 2 * p + 1]);
        h2 xb = pkh(B[mt][q0 + 2 * p], B[mt][q0 + 2 * p + 1]);
        h2 ya = (xa * iA2 + nA2) * g2 + e2;
        h2 yb = (xb * iB2 + nB2) * g2 + e2;
        ya = __builtin_elementwise_max(ya, ya * c02);
        yb = __builtin_elementwise_max(yb, yb * c02);
        PA[p] = hbits(ya);
        PB[p] = hbits(yb);
      }
      auto sa1 = __builtin_amdgcn_permlane32_swap((int)PA[0], (int)PA[2], false, false);
      auto sa2 = __builtin_amdgcn_permlane32_swap((int)PA[1], (int)PA[3], false, false);
      auto sb1 = __builtin_amdgcn_permlane32_swap((int)PB[0], (int)PB[2], false, false);
      auto sb2 = __builtin_amdgcn_permlane32_swap((int)PB[1], (int)PB[3], false, false);
      kinA[2 * mt + t2] = mkfrag((u32)sa1[0], (u32)sa2[0], (u32)sa1[1], (u32)sa2[1]);
      kinB[2 * mt + t2] = mkfrag((u32)sb1[0], (u32)sb2[0], (u32)sb1[1], (u32)sb2[1]);
    }
}

// bias + pack straight into B-frags (g3 output: no LN/act). Packed-f32 adds.
__device__ __forceinline__ void bias_pack64_dual(const f32x16* A, const f32x16* B,
                                                 const float* __restrict__ bias,
                                                 int lane, half8* kinA,
                                                 half8* kinB) {
  const int h = (lane >> 5) & 1;
#pragma unroll
  for (int mt = 0; mt < 2; ++mt)
#pragma unroll
    for (int t2 = 0; t2 < 2; ++t2) {
      const int q0 = t2 * 8;
      const float4 b0 = *(const float4*)(bias + 32 * mt + 2 * q0 + 4 * h);
      const float4 b1 = *(const float4*)(bias + 32 * mt + 2 * q0 + 8 + 4 * h);
      const f2 BBp[4] = {{b0.x, b0.y}, {b0.z, b0.w}, {b1.x, b1.y}, {b1.z, b1.w}};
      u32 PA[4], PB[4];
#pragma unroll
      for (int p = 0; p < 4; ++p) {
        PA[p] = hbits(pkh2(f2{A[mt][q0 + 2 * p], A[mt][q0 + 2 * p + 1]} + BBp[p]));
        PB[p] = hbits(pkh2(f2{B[mt][q0 + 2 * p], B[mt][q0 + 2 * p + 1]} + BBp[p]));
      }
      auto sa1 = __builtin_amdgcn_permlane32_swap((int)PA[0], (int)PA[2], false, false);
      auto sa2 = __builtin_amdgcn_permlane32_swap((int)PA[1], (int)PA[3], false, false);
      auto sb1 = __builtin_amdgcn_permlane32_swap((int)PB[0], (int)PB[2], false, false);
      auto sb2 = __builtin_amdgcn_permlane32_swap((int)PB[1], (int)PB[3], false, false);
      kinA[2 * mt + t2] = mkfrag((u32)sa1[0], (u32)sa2[0], (u32)sa1[1], (u32)sa2[1]);
      kinB[2 * mt + t2] = mkfrag((u32)sb1[0], (u32)sb2[0], (u32)sb1[1], (u32)sb2[1]);
    }
}

// Dual fused [64->128 + bias + LN + lrelu] streamed into [128->64].
// Two-pass LN (packed-f32 stats); pass 2 recompute + packed f16 affine.
__device__ __forceinline__ void fused128_dual(
    const half8* kinA, const half8* kinB, const float* __restrict__ bias,
    const float* __restrict__ gam, const float* __restrict__ bet,
    const uint4* __restrict__ lds, int inOff, int outOff, f32x16* outA,
    f32x16* outB, int lane) {
  const int h = (lane >> 5) & 1;
  f2 sA2 = {0.f, 0.f}, qA2 = {0.f, 0.f}, sB2 = {0.f, 0.f}, qB2 = {0.f, 0.f};
  // ---- pass 1: stats only (packed f32) ----
#pragma unroll 1
  for (int mt = 0; mt < 4; ++mt) {
    f32x16 a = zero16(), b = zero16();
#pragma unroll
    for (int ks = 0; ks < 4; ++ks) {
      const half8 wf = rdfrag(lds, inOff + mt * 4 + ks, lane);
      a = MFMA(wf, kinA[ks], a, 0, 0, 0);
      b = MFMA(wf, kinB[ks], b, 0, 0, 0);
    }
#pragma unroll
    for (int rq = 0; rq < 4; ++rq) {
      const float4 b4 = *(const float4*)(bias + 32 * mt + 8 * rq + 4 * h);
      const f2 b01 = {b4.x, b4.y}, b23 = {b4.z, b4.w};
      f2 va01 = f2{a[4 * rq + 0], a[4 * rq + 1]} + b01;
      f2 va23 = f2{a[4 * rq + 2], a[4 * rq + 3]} + b23;
      f2 vb01 = f2{b[4 * rq + 0], b[4 * rq + 1]} + b01;
      f2 vb23 = f2{b[4 * rq + 2], b[4 * rq + 3]} + b23;
      sA2 += va01 + va23;
      qA2 = va01 * va01 + qA2;
      qA2 = va23 * va23 + qA2;
      sB2 += vb01 + vb23;
      qB2 = vb01 * vb01 + qB2;
      qB2 = vb23 * vb23 + qB2;
    }
  }
  float sA = sA2.x + sA2.y, qA = qA2.x + qA2.y;
  float sB = sB2.x + sB2.y, qB = qB2.x + qB2.y;
  sA += __shfl_xor(sA, 32); qA += __shfl_xor(qA, 32);
  sB += __shfl_xor(sB, 32); qB += __shfl_xor(qB, 32);
  const float mA = sA * (1.f / 128.f);
  const float iA = rsqrtf(qA * (1.f / 128.f) - mA * mA + EPS);
  const float mB = sB * (1.f / 128.f);
  const float iB = rsqrtf(qB * (1.f / 128.f) - mB * mB + EPS);
  const h2 iA2 = pkh(iA, iA), nA2 = pkh(-mA * iA, -mA * iA);
  const h2 iB2 = pkh(iB, iB), nB2 = pkh(-mB * iB, -mB * iB);
  const h2 c02 = pkh(0.2f, 0.2f);
  asm volatile("" ::: "memory");  // no load CSE between pass 1 and pass 2
  // ---- pass 2: recompute, packed bias+affine, stream into OUT layer ----
  outA[0] = zero16(); outA[1] = zero16();
  outB[0] = zero16(); outB[1] = zero16();
#pragma unroll 1
  for (int mt = 0; mt < 4; ++mt) {
    f32x16 a = zero16(), b = zero16();
#pragma unroll
    for (int ks = 0; ks < 4; ++ks) {
      const half8 wf = rdfrag(lds, inOff + mt * 4 + ks, lane);
      a = MFMA(wf, kinA[ks], a, 0, 0, 0);
      b = MFMA(wf, kinB[ks], b, 0, 0, 0);
    }
#pragma unroll
    for (int u = 0; u < 2; ++u) {
      const int c0 = 32 * mt + 16 * u + 4 * h;
      const float4 ba4 = *(const float4*)(bias + c0);
      const float4 bb4 = *(const float4*)(bias + c0 + 8);
      const float4 ga4 = *(const float4*)(gam + c0);
      const float4 gb4 = *(const float4*)(gam + c0 + 8);
      const float4 ca4 = *(const float4*)(bet + c0);
      const float4 cb4 = *(const float4*)(bet + c0 + 8);
      const f2 BBp[4] = {{ba4.x, ba4.y}, {ba4.z, ba4.w}, {bb4.x, bb4.y}, {bb4.z, bb4.w}};
      const float GG[8] = {ga4.x, ga4.y, ga4.z, ga4.w, gb4.x, gb4.y, gb4.z, gb4.w};
      const float CC[8] = {ca4.x, ca4.y, ca4.z, ca4.w, cb4.x, cb4.y, cb4.z, cb4.w};
      u32 PA[4], PB[4];
#pragma unroll
      for (int p = 0; p < 4; ++p) {
        const h2 g2 = pkh(GG[2 * p], GG[2 * p + 1]);
        const h2 e2 = pkh(CC[2 * p], CC[2 * p + 1]);
        h2 xa = pkh2(f2{a[8 * u + 2 * p], a[8 * u + 2 * p + 1]} + BBp[p]);
        h2 xb = pkh2(f2{b[8 * u + 2 * p], b[8 * u + 2 * p + 1]} + BBp[p]);
        h2 ya = (xa * iA2 + nA2) * g2 + e2;
        h2 yb = (xb * iB2 + nB2) * g2 + e2;
        ya = __builtin_elementwise_max(ya, ya * c02);
        yb = __builtin_elementwise_max(yb, yb * c02);
        PA[p] = hbits(ya);
        PB[p] = hbits(yb);
      }
      auto sa1 = __builtin_amdgcn_permlane32_swap((int)PA[0], (int)PA[2], false, false);
      auto sa2 = __builtin_amdgcn_permlane32_swap((int)PA[1], (int)PA[3], false, false);
      auto sb1 = __builtin_amdgcn_permlane32_swap((int)PB[0], (int)PB[2], false, false);
      auto sb2 = __builtin_amdgcn_permlane32_swap((int)PB[1], (int)PB[3], false, false);
      const half8 frA = mkfrag((u32)sa1[0], (u32)sa2[0], (u32)sa1[1], (u32)sa2[1]);
      const half8 frB = mkfrag((u32)sb1[0], (u32)sb2[0], (u32)sb1[1], (u32)sb2[1]);
      const int t = 2 * mt + u;
      const half8 w0 = rdfrag(lds, outOff + t, lane);
      const half8 w1 = rdfrag(lds, outOff + 8 + t, lane);
      outA[0] = MFMA(w0, frA, outA[0], 0, 0, 0);
      outA[1] = MFMA(w1, frA, outA[1], 0, 0, 0);
      outB[0] = MFMA(w0, frB, outB[0], 0, 0, 0);
      outB[1] = MFMA(w1, frB, outB[1], 0, 0, 0);
    }
  }
}

extern "C" __global__ void __launch_bounds__(TB)
    __attribute__((amdgpu_waves_per_eu(2, 2)))  // 2 waves/EU -> 256-VGPR budget
lfa_mfma(const float* __restrict__ pf, const float* __restrict__ geom,
         const int* __restrict__ nidx,
         const float* __restrict__ g_w1, const float* __restrict__ g_b1,
         const float* __restrict__ g_ls1, const float* __restrict__ g_lb1,
         const float* __restrict__ g_w2, const float* __restrict__ g_b2,
         const float* __restrict__ g_ls2, const float* __restrict__ g_lb2,
         const float* __restrict__ g_w3, const float* __restrict__ g_b3,
         const float* __restrict__ f_w1, const float* __restrict__ f_b1,
         const float* __restrict__ f_ls1, const float* __restrict__ f_lb1,
         const float* __restrict__ f_w2, const float* __restrict__ f_b2,
         const float* __restrict__ f_ls2, const float* __restrict__ f_lb2,
         const float* __restrict__ f_w3, const float* __restrict__ f_b3,
         float* __restrict__ out) {
  extern __shared__ uint4 lds[];
  const int tid = threadIdx.x;

  stage<64, 128>(g_w2, lds, OFF_G2, 1.f, tid);
  stage<128, 64>(g_w3, lds, OFF_G3, 1.f, tid);
  stage<128, 64>(f_w1, lds, OFF_F1, 1.f, tid);
  stage<64, 128>(f_w2, lds, OFF_F2, 1.f, tid);
  stage<128, 64>(f_w3, lds, OFF_W3, 1.f / 16.f, tid);  // fold mean over K
  __syncthreads();

  const int lane = tid & 63;
  const int w = tid >> 6;
  const int h = lane >> 5;
  const int p31 = lane & 31;

  // gL1 A-frags (4 -> 64, K padded to 16)
  half8 a1[2];
#pragma unroll
  for (int mt = 0; mt < 2; ++mt) {
    const int och = 32 * mt + p31;
    a1[mt] = mkfrag(h ? 0u : hbits(pkh(g_w1[0 * 64 + och], g_w1[1 * 64 + och])),
                    h ? 0u : hbits(pkh(g_w1[2 * 64 + och], g_w1[3 * 64 + och])),
                    0u, 0u);
  }

  half8 kinA[4], kinB[4];

  for (int t0 = blockIdx.x * WPB + w; t0 < NN; t0 += 2 * STR) {
    asm volatile("" ::: "memory");  // forbid LICM of any in-loop load
    const int tileA = t0;
    const bool hasB = (t0 + STR) < NN;            // wave-uniform
    const int tileB = hasB ? (t0 + STR) : tileA;  // redundant compute on tail
    const int rrowA = tileA * 32 + p31;
    const int rrowB = tileB * 32 + p31;
    const int bbA = tileA / 25000;
    const int bbB = tileB / 25000;

    // early-issue gather indices (addresses ready under the geom phase)
    const int idxA = nidx[rrowA];
    const int idxB = nidx[rrowB];
    const float* prA = pf + ((size_t)bbA * NN + idxA) * 64;
    const float* prB = pf + ((size_t)bbB * NN + idxB) * 64;

    // ---- geom L1: 4 -> 64 (dual) ----
    const float4 gA = *(const float4*)(geom + (size_t)rrowA * 4);
    const float4 gB = *(const float4*)(geom + (size_t)rrowB * 4);
    const half8 gfA = mkfrag(h ? 0u : hbits(pkh(gA.x, gA.y)),
                             h ? 0u : hbits(pkh(gA.z, gA.w)), 0u, 0u);
    const half8 gfB = mkfrag(h ? 0u : hbits(pkh(gB.x, gB.y)),
                             h ? 0u : hbits(pkh(gB.z, gB.w)), 0u, 0u);
    f32x16 accA[2], accB[2];
#pragma unroll
    for (int mt = 0; mt < 2; ++mt) {
      accA[mt] = MFMA(a1[mt], gfA, zero16(), 0, 0, 0);
      accB[mt] = MFMA(a1[mt], gfB, zero16(), 0, 0, 0);
    }
    ln_pack64_dual(accA, accB, g_b1, g_ls1, g_lb1, lane, kinA, kinB);

    // ---- geom L2 -> geom L3 (dual fused) ----
    fused128_dual(kinA, kinB, g_b2, g_ls2, g_lb2, lds, OFF_G2, OFF_G3, accA,
                  accB, lane);
    bias_pack64_dual(accA, accB, g_b3, lane, kinA, kinB);

    // ---- feat L1: 128 -> 64 (dual; first half from kin, gather streamed) ----
#pragma unroll
    for (int mt = 0; mt < 2; ++mt) {
      f32x16 ta = zero16(), tb = zero16();
#pragma unroll
      for (int ks = 0; ks < 4; ++ks) {
        const half8 wf = rdfrag(lds, OFF_F1 + mt * 8 + ks, lane);
        ta = MFMA(wf, kinA[ks], ta, 0, 0, 0);
        tb = MFMA(wf, kinB[ks], tb, 0, 0, 0);
      }
      accA[mt] = ta;
      accB[mt] = tb;
    }
    {
#pragma unroll
      for (int t = 0; t < 4; ++t) {
        const float4 xA = *(const float4*)(prA + 16 * t + 8 * h);
        const float4 yA = *(const float4*)(prA + 16 * t + 8 * h + 4);
        const float4 xB = *(const float4*)(prB + 16 * t + 8 * h);
        const float4 yB = *(const float4*)(prB + 16 * t + 8 * h + 4);
        const half8 fA = mkfrag(hbits(pkh(xA.x, xA.y)), hbits(pkh(xA.z, xA.w)),
                                hbits(pkh(yA.x, yA.y)), hbits(pkh(yA.z, yA.w)));
        const half8 fB = mkfrag(hbits(pkh(xB.x, xB.y)), hbits(pkh(xB.z, xB.w)),
                                hbits(pkh(yB.x, yB.y)), hbits(pkh(yB.z, yB.w)));
        const half8 w0 = rdfrag(lds, OFF_F1 + 4 + t, lane);
        const half8 w1 = rdfrag(lds, OFF_F1 + 12 + t, lane);
        accA[0] = MFMA(w0, fA, accA[0], 0, 0, 0);
        accA[1] = MFMA(w1, fA, accA[1], 0, 0, 0);
        accB[0] = MFMA(w0, fB, accB[0], 0, 0, 0);
        accB[1] = MFMA(w1, fB, accB[1], 0, 0, 0);
      }
    }
    ln_pack64_dual(accA, accB, f_b1, f_ls1, f_lb1, lane, kinA, kinB);

    // ---- feat L2 -> final/16 (dual fused) ----
    fused128_dual(kinA, kinB, f_b2, f_ls2, f_lb2, lds, OFF_F2, OFF_W3, accA,
                  accB, lane);

    // ---- sum over 16 k-columns (both), add f_b3 at store ----
#pragma unroll
    for (int mt = 0; mt < 2; ++mt)
#pragma unroll
      for (int r = 0; r < 16; ++r) {
        float va = accA[mt][r];
        float vb = accB[mt][r];
        va += __shfl_xor(va, 1); vb += __shfl_xor(vb, 1);
        va += __shfl_xor(va, 2); vb += __shfl_xor(vb, 2);
        va += __shfl_xor(va, 4); vb += __shfl_xor(vb, 4);
        va += __shfl_xor(va, 8); vb += __shfl_xor(vb, 8);
        accA[mt][r] = va;
        accB[mt][r] = vb;
      }
    if ((lane & 15) < 4) {
      const int c = lane & 15;
      const int bn = (lane >> 4) & 1;
      const size_t rowA = (size_t)tileA * 2 + bn;
      const size_t rowB = (size_t)tileB * 2 + bn;
#pragma unroll
      for (int mt = 0; mt < 2; ++mt) {
        const float4 bq = *(const float4*)(f_b3 + 32 * mt + 8 * c + 4 * h);
        const float4 vA =
            (c == 0) ? make_float4(accA[mt][0], accA[mt][1], accA[mt][2], accA[mt][3])
          : (c == 1) ? make_float4(accA[mt][4], accA[mt][5], accA[mt][6], accA[mt][7])
          : (c == 2) ? make_float4(accA[mt][8], accA[mt][9], accA[mt][10], accA[mt][11])
                     : make_float4(accA[mt][12], accA[mt][13], accA[mt][14], accA[mt][15]);
        *(float4*)(out + rowA * 64 + 32 * mt + 8 * c + 4 * h) =
            make_float4(vA.x + bq.x, vA.y + bq.y, vA.z + bq.z, vA.w + bq.w);
        if (hasB) {
          const float4 vB =
              (c == 0) ? make_float4(accB[mt][0], accB[mt][1], accB[mt][2], accB[mt][3])
            : (c == 1) ? make_float4(accB[mt][4], accB[mt][5], accB[mt][6], accB[mt][7])
            : (c == 2) ? make_float4(accB[mt][8], accB[mt][9], accB[mt][10], accB[mt][11])
                       : make_float4(accB[mt][12], accB[mt][13], accB[mt][14], accB[mt][15]);
          *(float4*)(out + rowB * 64 + 32 * mt + 8 * c + 4 * h) =
              make_float4(vB.x + bq.x, vB.y + bq.y, vB.z + bq.z, vB.w + bq.w);
        }
      }
    }
  }
}

extern "C" void kernel_launch(void* const* d_in, const int* in_sizes, int n_in,
                              void* d_out, int out_size, void* d_ws, size_t ws_size,
                              hipStream_t stream) {
  const float* pf = (const float*)d_in[0];
  const float* geom = (const float*)d_in[1];
  const int* nidx = (const int*)d_in[2];
  const float* g_w1 = (const float*)d_in[3];
  const float* g_b1 = (const float*)d_in[4];
  const float* g_ls1 = (const float*)d_in[5];
  const float* g_lb1 = (const float*)d_in[6];
  const float* g_w2 = (const float*)d_in[7];
  const float* g_b2 = (const float*)d_in[8];
  const float* g_ls2 = (const float*)d_in[9];
  const float* g_lb2 = (const float*)d_in[10];
  const float* g_w3 = (const float*)d_in[11];
  const float* g_b3 = (const float*)d_in[12];
  const float* f_w1 = (const float*)d_in[13];
  const float* f_b1 = (const float*)d_in[14];
  const float* f_ls1 = (const float*)d_in[15];
  const float* f_lb1 = (const float*)d_in[16];
  const float* f_w2 = (const float*)d_in[17];
  const float* f_b2 = (const float*)d_in[18];
  const float* f_ls2 = (const float*)d_in[19];
  const float* f_lb2 = (const float*)d_in[20];
  const float* f_w3 = (const float*)d_in[21];
  const float* f_b3 = (const float*)d_in[22];

  const int shmem = NFRAGS * 64 * 16;  // 81920 B
  lfa_mfma<<<NBLK, TB, shmem, stream>>>(
      pf, geom, nidx, g_w1, g_b1, g_ls1, g_lb1, g_w2, g_b2, g_ls2, g_lb2, g_w3,
      g_b3, f_w1, f_b1, f_ls1, f_lb1, f_w2, f_b2, f_ls2, f_lb2, f_w3, f_b3,
      (float*)d_out);
}